// Round 1
// baseline (772.736 us; speedup 1.0000x reference)
//
#include <hip/hip_runtime.h>
#include <hip/hip_bf16.h>

#define HW   4096
#define CDIM 512
#define CHALF 256
#define NB   4

using bf16 = __hip_bfloat16;
typedef __attribute__((ext_vector_type(8))) short short8;
typedef __attribute__((ext_vector_type(4))) float float4v;

static __device__ __forceinline__ short8 ld_short8(const bf16* p) {
    return *reinterpret_cast<const short8*>(p);
}

// ---------------------------------------------------------------------------
// Transpose + cast: Fc[b][c][p] fp32 -> FcT[b][p][c] bf16 (and Fs -> FsT)
// ---------------------------------------------------------------------------
__global__ void transpose_cast(const float* __restrict__ Fc,
                               const float* __restrict__ Fs,
                               bf16* __restrict__ FcT, bf16* __restrict__ FsT) {
    __shared__ float tile[32][33];
    int p0 = blockIdx.x * 32, c0 = blockIdx.y * 32;
    int z = blockIdx.z;
    int b = z & 3, which = z >> 2;
    const float* src = (which ? Fs : Fc) + (size_t)b * CDIM * HW;
    bf16* dst = (which ? FsT : FcT) + (size_t)b * HW * CDIM;
    int tx = threadIdx.x, ty = threadIdx.y;  // (32,8)
    for (int i = 0; i < 4; i++)
        tile[ty + 8 * i][tx] = src[(size_t)(c0 + ty + 8 * i) * HW + p0 + tx];
    __syncthreads();
    for (int i = 0; i < 4; i++)
        dst[(size_t)(p0 + ty + 8 * i) * CDIM + c0 + tx] =
            __float2bfloat16(tile[tx][ty + 8 * i]);
}

__global__ void cast_scale(const float* __restrict__ s, bf16* __restrict__ d,
                           int n, float scale) {
    int i = blockIdx.x * blockDim.x + threadIdx.x;
    int stride = gridDim.x * blockDim.x;
    for (; i < n; i += stride) d[i] = __float2bfloat16(s[i] * scale);
}

// ---------------------------------------------------------------------------
// Generic bf16 MFMA GEMM: D[m][n] = sum_k A[m][k]*B[n][k] + bias (+resid)
// A: [M][K] k-fastest, B: [N][K] k-fastest. Tile 128x128, BK=64, 256 thr.
// bias_on_m: bias indexed by m (else by n). out_f32: write fp32 else bf16.
// ---------------------------------------------------------------------------
__launch_bounds__(256, 2)
__global__ void gemm_bf16(const bf16* __restrict__ A, size_t sA,
                          const bf16* __restrict__ Bm, size_t sB,
                          const float* __restrict__ bias, int bias_on_m,
                          float bscale,
                          const float* __restrict__ resid, size_t sR,
                          void* __restrict__ Dp, size_t sD, int out_f32,
                          int M, int N, int K) {
    __shared__ bf16 As[128][72];
    __shared__ bf16 Bs[128][72];
    int b = blockIdx.z;
    A += sA * b;
    Bm += sB * b;
    int m0 = blockIdx.y * 128, n0 = blockIdx.x * 128;
    int t = threadIdx.x;
    int w = t >> 6, lane = t & 63;
    int wm = w >> 1, wn = w & 1;
    int l15 = lane & 15, quad = lane >> 4;
    float4v acc[4][4] = {};

    for (int k0 = 0; k0 < K; k0 += 64) {
        for (int i = 0; i < 4; i++) {
            int chunk = t + 256 * i;
            int row = chunk >> 3, c8 = (chunk & 7) * 8;
            *(short8*)&As[row][c8] = ld_short8(A + (size_t)(m0 + row) * K + k0 + c8);
            *(short8*)&Bs[row][c8] = ld_short8(Bm + (size_t)(n0 + row) * K + k0 + c8);
        }
        __syncthreads();
        for (int kk = 0; kk < 64; kk += 32) {
            int kc = kk + quad * 8;
            short8 af[4], bfr[4];
            for (int sm = 0; sm < 4; sm++)
                af[sm] = *(const short8*)&As[wm * 64 + sm * 16 + l15][kc];
            for (int sn = 0; sn < 4; sn++)
                bfr[sn] = *(const short8*)&Bs[wn * 64 + sn * 16 + l15][kc];
            for (int sm = 0; sm < 4; sm++)
                for (int sn = 0; sn < 4; sn++)
                    acc[sm][sn] = __builtin_amdgcn_mfma_f32_16x16x32_bf16(
                        af[sm], bfr[sn], acc[sm][sn], 0, 0, 0);
        }
        __syncthreads();
    }

    const float* rs = resid ? resid + sR * b : nullptr;
    for (int sm = 0; sm < 4; sm++) {
        for (int sn = 0; sn < 4; sn++) {
            int n = n0 + wn * 64 + sn * 16 + l15;
            for (int r = 0; r < 4; r++) {
                int m = m0 + wm * 64 + sm * 16 + quad * 4 + r;
                float v = acc[sm][sn][r];
                v += (bias_on_m ? bias[m] : bias[n]) * bscale;
                if (rs) v += rs[(size_t)m * N + n];
                if (out_f32)
                    ((float*)Dp)[sD * b + (size_t)m * N + n] = v;
                else
                    ((bf16*)Dp)[sD * b + (size_t)m * N + n] = __float2bfloat16(v);
            }
        }
    }
}

// ---------------------------------------------------------------------------
// Flash attention: per block one 64-row Q tile of one batch. 512 thr, 8 waves.
// Q = FfT[b][i][c] (scale folded), K = FgT[b][j][c], V = Fh[b][c][j].
// O[b][i][c] written bf16.
// ---------------------------------------------------------------------------
__launch_bounds__(512, 1)
__global__ void flash_attn(const bf16* __restrict__ Q_, const bf16* __restrict__ Kt_,
                           const bf16* __restrict__ V_, bf16* __restrict__ O_) {
    __shared__ bf16 Ks[64][264];
    __shared__ float Ss[64][68];
    __shared__ bf16 Ps[64][72];
    __shared__ float mrow[64], lrow[64], arow[64];

    int b = blockIdx.y;
    int i0 = blockIdx.x * 64;
    const bf16* Q  = Q_ + ((size_t)b * HW + i0) * CHALF;
    const bf16* Kt = Kt_ + (size_t)b * HW * CHALF;
    const bf16* V  = V_ + (size_t)b * CDIM * HW;
    bf16* Out = O_ + ((size_t)b * HW + i0) * CDIM;

    int t = threadIdx.x;
    int w = t >> 6, lane = t & 63;
    int l15 = lane & 15, quad = lane >> 4;
    int smw = w & 3;          // this wave's S m-subtile (rows 16*smw..)
    int snb = (w >> 2) * 2;   // this wave's S n-subtile base (2 subtiles)
    int c0w = w * 64;         // this wave's V channel slice

    // preload Q A-fragments for this wave's m-subtile (all K=256)
    short8 qf[8];
    {
        const bf16* qp = Q + (size_t)(smw * 16 + l15) * CHALF + quad * 8;
        for (int k8 = 0; k8 < 8; k8++) qf[k8] = ld_short8(qp + k8 * 32);
    }
    if (t < 64) { mrow[t] = -1e30f; lrow[t] = 0.f; }
    float4v oacc[4][4] = {};
    __syncthreads();

    for (int j0 = 0; j0 < HW; j0 += 64) {
        // stage K tile [64][256]
        for (int i = 0; i < 4; i++) {
            int chunk = t + 512 * i;
            int row = chunk >> 5, c8 = (chunk & 31) * 8;
            *(short8*)&Ks[row][c8] = ld_short8(Kt + (size_t)(j0 + row) * CHALF + c8);
        }
        __syncthreads();

        // S = Q K^T (scaled already); each wave: 2 subtiles
        for (int tt = 0; tt < 2; tt++) {
            int sn = snb + tt;
            float4v s = {};
            for (int k8 = 0; k8 < 8; k8++) {
                short8 kf = *(const short8*)&Ks[sn * 16 + l15][k8 * 32 + quad * 8];
                s = __builtin_amdgcn_mfma_f32_16x16x32_bf16(qf[k8], kf, s, 0, 0, 0);
            }
            for (int r = 0; r < 4; r++)
                Ss[smw * 16 + quad * 4 + r][sn * 16 + l15] = s[r];
        }
        __syncthreads();

        // online softmax: 8 threads per row
        {
            int row = t >> 3, l8 = t & 7;
            float v[8];
            for (int q = 0; q < 8; q++) v[q] = Ss[row][l8 * 8 + q];
            float mx = v[0];
            for (int q = 1; q < 8; q++) mx = fmaxf(mx, v[q]);
            mx = fmaxf(mx, __shfl_xor(mx, 1));
            mx = fmaxf(mx, __shfl_xor(mx, 2));
            mx = fmaxf(mx, __shfl_xor(mx, 4));
            float mold = mrow[row];
            float mnew = fmaxf(mold, mx);
            float sum = 0.f;
            for (int q = 0; q < 8; q++) {
                float p = __expf(v[q] - mnew);
                sum += p;
                Ps[row][l8 * 8 + q] = __float2bfloat16(p);
            }
            sum += __shfl_xor(sum, 1);
            sum += __shfl_xor(sum, 2);
            sum += __shfl_xor(sum, 4);
            if (l8 == 0) {
                arow[row] = __expf(mold - mnew);
                lrow[row] = lrow[row] * arow[row] + sum;
                mrow[row] = mnew;
            }
        }
        __syncthreads();

        // rescale O, then O += P * V (wave's 64-channel slice)
        for (int sm = 0; sm < 4; sm++)
            for (int r = 0; r < 4; r++) {
                float a = arow[sm * 16 + quad * 4 + r];
                for (int sn = 0; sn < 4; sn++) oacc[sm][sn][r] *= a;
            }
        for (int kk = 0; kk < 64; kk += 32) {
            short8 vf[4];
            for (int sn = 0; sn < 4; sn++)
                vf[sn] = ld_short8(V + (size_t)(c0w + sn * 16 + l15) * HW + j0 + kk + quad * 8);
            for (int sm = 0; sm < 4; sm++) {
                short8 pf = *(const short8*)&Ps[sm * 16 + l15][kk + quad * 8];
                for (int sn = 0; sn < 4; sn++)
                    oacc[sm][sn] = __builtin_amdgcn_mfma_f32_16x16x32_bf16(
                        pf, vf[sn], oacc[sm][sn], 0, 0, 0);
            }
        }
        __syncthreads();
    }

    // epilogue: normalize and store O[i][c] bf16
    for (int sm = 0; sm < 4; sm++) {
        float linv[4];
        for (int r = 0; r < 4; r++) linv[r] = 1.0f / lrow[sm * 16 + quad * 4 + r];
        for (int sn = 0; sn < 4; sn++)
            for (int r = 0; r < 4; r++) {
                float vv = oacc[sm][sn][r] * linv[r];
                Out[(size_t)(sm * 16 + quad * 4 + r) * CDIM + c0w + sn * 16 + l15] =
                    __float2bfloat16(vv);
            }
    }
}

// ---------------------------------------------------------------------------
extern "C" void kernel_launch(void* const* d_in, const int* in_sizes, int n_in,
                              void* d_out, int out_size, void* d_ws, size_t ws_size,
                              hipStream_t stream) {
    const float* Fc   = (const float*)d_in[0];
    const float* Fs   = (const float*)d_in[1];
    const float* f_w  = (const float*)d_in[2];
    const float* f_b  = (const float*)d_in[3];
    const float* g_w  = (const float*)d_in[4];
    const float* g_b  = (const float*)d_in[5];
    const float* h_w  = (const float*)d_in[6];
    const float* h_b  = (const float*)d_in[7];
    const float* out_w = (const float*)d_in[8];
    const float* out_b = (const float*)d_in[9];
    float* out = (float*)d_out;

    bf16* FcT = (bf16*)d_ws;                          // [B][4096][512]
    bf16* FsT = FcT + (size_t)NB * HW * CDIM;         // [B][4096][512]
    bf16* FfT = FsT + (size_t)NB * HW * CDIM;         // [B][4096][256]
    bf16* FgT = FfT + (size_t)NB * HW * CHALF;        // [B][4096][256]
    bf16* Fh  = FgT + (size_t)NB * HW * CHALF;        // [B][512][4096]
    bf16* Ob  = Fh  + (size_t)NB * CDIM * HW;         // [B][4096][512]
    bf16* fw  = Ob  + (size_t)NB * HW * CDIM;
    bf16* gw  = fw + (size_t)CHALF * CDIM;
    bf16* hw  = gw + (size_t)CHALF * CDIM;
    bf16* ow  = hw + (size_t)CDIM * CDIM;

    transpose_cast<<<dim3(HW / 32, CDIM / 32, NB * 2), dim3(32, 8), 0, stream>>>(
        Fc, Fs, FcT, FsT);
    cast_scale<<<dim3(64), dim3(256), 0, stream>>>(f_w, fw, CHALF * CDIM, 0.0625f);
    cast_scale<<<dim3(64), dim3(256), 0, stream>>>(g_w, gw, CHALF * CDIM, 1.0f);
    cast_scale<<<dim3(128), dim3(256), 0, stream>>>(h_w, hw, CDIM * CDIM, 1.0f);
    cast_scale<<<dim3(128), dim3(256), 0, stream>>>(out_w, ow, CDIM * CDIM, 1.0f);

    // FfT[p][o] = FcT x f_w^T  (M=4096, N=256, K=512), bias on n, 1/16 folded
    gemm_bf16<<<dim3(2, 32, NB), 256, 0, stream>>>(
        FcT, (size_t)HW * CDIM, fw, 0, f_b, 0, 0.0625f, nullptr, 0,
        FfT, (size_t)HW * CHALF, 0, HW, CHALF, CDIM);
    // FgT[p][o] = FsT x g_w^T
    gemm_bf16<<<dim3(2, 32, NB), 256, 0, stream>>>(
        FsT, (size_t)HW * CDIM, gw, 0, g_b, 0, 1.0f, nullptr, 0,
        FgT, (size_t)HW * CHALF, 0, HW, CHALF, CDIM);
    // Fh[o][p] = h_w x Fs  (M=512, N=4096, K=512), bias on m
    gemm_bf16<<<dim3(32, 4, NB), 256, 0, stream>>>(
        hw, 0, FsT, (size_t)HW * CDIM, h_b, 1, 1.0f, nullptr, 0,
        Fh, (size_t)CDIM * HW, 0, CDIM, HW, CDIM);
    // flash attention -> Ob[i][c]
    flash_attn<<<dim3(HW / 64, NB), 512, 0, stream>>>(FfT, FgT, Fh, Ob);
    // out[co][i] = out_w x O + out_b + Fc  (M=512, N=4096, K=512), fp32 out
    gemm_bf16<<<dim3(32, 4, NB), 256, 0, stream>>>(
        ow, 0, Ob, (size_t)HW * CDIM, out_b, 1, 1.0f, Fc, (size_t)CDIM * HW,
        out, (size_t)CDIM * HW, 1, CDIM, HW, CDIM);
}